// Round 2
// baseline (4873.767 us; speedup 1.0000x reference)
//
#include <hip/hip_runtime.h>
#include <math.h>

#define TSTEPS 1024
#define BATCH  512
#define HID    64
#define VOC    29
#define SOS    27
#define MASK29 0x1FFFFFFFu

#define ENC_BLOCKS 256
#define DEC_BLOCKS 256
#define NTHREADS   512
#define WMAX       16

__device__ __forceinline__ float frcp(float x){ return __builtin_amdgcn_rcpf(x); }
__device__ __forceinline__ float sigmf(float x){ return frcp(1.0f + __expf(-x)); }
__device__ __forceinline__ float tanhfast(float x){ return 1.0f - 2.0f*frcp(1.0f + __expf(2.0f*x)); }

// ---------------- Encoder: cross-layer pipelined 2-layer LSTM, 2 rows/block ----------------
// (unchanged)
__global__ __attribute__((amdgpu_flat_work_group_size(NTHREADS,NTHREADS), amdgpu_waves_per_eu(2,2)))
void enc_kernel(const float* __restrict__ x,
                const float* __restrict__ Wih0, const float* __restrict__ Whh0,
                const float* __restrict__ bih0, const float* __restrict__ bhh0,
                const float* __restrict__ Wih1, const float* __restrict__ Whh1,
                const float* __restrict__ bih1, const float* __restrict__ bhh1,
                float* __restrict__ h1g, float* __restrict__ c1g)
{
  const int tid = threadIdx.x;
  const int b0  = blockIdx.x * 2;
  const bool g0 = tid < 256;
  const int  r  = g0 ? tid : (tid-256);

  __shared__ __align__(16) float xs[2][32];
  __shared__ __align__(16) float h0s[2][HID], h1s[2][HID];
  __shared__ __align__(16) float gA[2][256], gB[2][256];

  float wh[64], w2[64];
  if (g0){
    #pragma unroll
    for (int k=0;k<64;k++) wh[k] = Whh0[r*64+k];
    #pragma unroll
    for (int k=0;k<29;k++) w2[k] = Wih0[r*29+k];
    #pragma unroll
    for (int k=29;k<64;k++) w2[k] = 0.f;
  } else {
    #pragma unroll
    for (int k=0;k<64;k++){ wh[k] = Whh1[r*64+k]; w2[k] = Wih1[r*64+k]; }
  }
  const float bias = g0 ? (bih0[r]+bhh0[r]) : (bih1[r]+bhh1[r]);

  float creg = 0.f;
  if (tid < 128){ int u=tid>>6,k=tid&63; h0s[u][k]=0.f; h1s[u][k]=0.f; }

  const int pidx = tid - 448;
  const bool pf  = (pidx >= 0) && (pidx < 2*VOC);
  const int prow = pf ? (pidx/VOC) : 0;
  const int pcol = pf ? (pidx%VOC) : 0;
  if (pf) xs[prow][pcol] = x[(size_t)(b0+prow)*VOC + pcol];
  __syncthreads();

  for (int t=0;t<=TSTEPS;t++){
    float xv = 0.f;
    if (pf && t+1 < TSTEPS)
      xv = x[(size_t)(t+1)*BATCH*VOC + (size_t)(b0+prow)*VOC + pcol];

    if (g0){
      if (t < TSTEPS){
        #pragma unroll
        for (int u=0;u<2;u++){
          float a0=bias,a1=0.f,a2=0.f,a3=0.f;
          const float4* xv4 = (const float4*)xs[u];
          #pragma unroll
          for (int c=0;c<7;c++){
            float4 q=xv4[c];
            a0=fmaf(q.x,w2[4*c+0],a0); a1=fmaf(q.y,w2[4*c+1],a1);
            a2=fmaf(q.z,w2[4*c+2],a2); a3=fmaf(q.w,w2[4*c+3],a3);
          }
          a0=fmaf(xs[u][28],w2[28],a0);
          const float4* h4=(const float4*)h0s[u];
          #pragma unroll
          for (int c=0;c<16;c++){
            float4 q=h4[c];
            a0=fmaf(q.x,wh[4*c+0],a0); a1=fmaf(q.y,wh[4*c+1],a1);
            a2=fmaf(q.z,wh[4*c+2],a2); a3=fmaf(q.w,wh[4*c+3],a3);
          }
          gA[u][r]=(a0+a1)+(a2+a3);
        }
      }
    } else {
      if (t >= 1){
        #pragma unroll
        for (int u=0;u<2;u++){
          float a0=bias,a1=0.f,a2=0.f,a3=0.f;
          const float4* i4=(const float4*)h0s[u];
          const float4* h4=(const float4*)h1s[u];
          #pragma unroll
          for (int c=0;c<16;c++){
            float4 q=i4[c], w=h4[c];
            a0=fmaf(q.x,w2[4*c+0],a0); a1=fmaf(q.y,w2[4*c+1],a1);
            a2=fmaf(q.z,w2[4*c+2],a2); a3=fmaf(q.w,w2[4*c+3],a3);
            a0=fmaf(w.x,wh[4*c+0],a0); a1=fmaf(w.y,wh[4*c+1],a1);
            a2=fmaf(w.z,wh[4*c+2],a2); a3=fmaf(w.w,wh[4*c+3],a3);
          }
          gB[u][r]=(a0+a1)+(a2+a3);
        }
      }
    }
    __syncthreads();
    if (tid < 128){
      if (t < TSTEPS){
        int u=tid>>6,k=tid&63;
        float ig=gA[u][k],fg=gA[u][64+k],gg=gA[u][128+k],og=gA[u][192+k];
        float c=sigmf(fg)*creg + sigmf(ig)*tanhfast(gg);
        creg=c; h0s[u][k]=sigmf(og)*tanhfast(c);
      }
    } else if (tid < 384){
      if (t >= 1){
        int tt=tid-256,u=tt>>6,k=tt&63;
        float ig=gB[u][k],fg=gB[u][64+k],gg=gB[u][128+k],og=gB[u][192+k];
        float c=sigmf(fg)*creg + sigmf(ig)*tanhfast(gg);
        creg=c; h1s[u][k]=sigmf(og)*tanhfast(c);
      }
    }
    if (pf && t+1 < TSTEPS) xs[prow][pcol] = xv;
    __syncthreads();
  }

  if (tid >= 256 && tid < 384){
    int tt=tid-256,u=tt>>6,k=tt&63;
    h1g[(b0+u)*HID+k]=h1s[u][k];
    c1g[(b0+u)*HID+k]=creg;
  }
}

// ---------------- Decoder v3: fused shuffle gates, per-step checkpoints, tagged u64 sync ----
// Pair r=tid>>1 (half p=tid&1) computes gate row g=(r&3)*64+(r>>2) so unit m=tid>>3's four
// gates live in 8 adjacent lanes -> gather via shfl_xor(2/4/6), activation computed by all
// lanes (redundant x8). 2 barriers/step. Per-step state checkpoints in LDS make rollback
// free (restore only, no recompute). Posts are self-tagged u64 {round+1, mask}: poll and
// mask-read fuse into a single spin phase.
__global__ __attribute__((amdgpu_flat_work_group_size(NTHREADS,NTHREADS), amdgpu_waves_per_eu(2,2)))
void dec_kernel(const float* __restrict__ h1gp, const float* __restrict__ c1gp,
                const float* __restrict__ W1ih, const float* __restrict__ W1hh,
                const float* __restrict__ b1ih, const float* __restrict__ b1hh,
                const float* __restrict__ W2ih, const float* __restrict__ W2hh,
                const float* __restrict__ b2ih, const float* __restrict__ b2hh,
                const float* __restrict__ clsW, const float* __restrict__ clsb,
                float* __restrict__ out,
                unsigned long long* __restrict__ mseq)
{
  const int tid  = threadIdx.x;
  const int p    = tid & 1;
  const int r    = tid >> 1;           // pair index 0..255
  const int q    = r & 3;              // gate quadrant (i,f,g,o)
  const int m    = tid >> 3;           // hidden unit 0..63
  const int g    = q*64 + m;           // gate row
  const int blk  = blockIdx.x;
  const int b0   = blk * 2;

  __shared__ __align__(16) float clsW_s[VOC][68];
  __shared__ __align__(16) float clsb_s[32];
  __shared__ __align__(16) float h1s[2][2][HID], h2s[2][2][HID];
  __shared__ __align__(16) float h1ck[WMAX][2][HID], c1ck[WMAX][2][HID];
  __shared__ __align__(16) float h2ck[WMAX][2][HID], c2ck[WMAX][2][HID];
  __shared__ unsigned u_lds[WMAX];

  for (int i=tid;i<VOC*HID;i+=NTHREADS) clsW_s[i/HID][i%HID] = clsW[i];
  if (tid<VOC) clsb_s[tid]=clsb[tid];

  // per-thread weight halves for gate row g
  float w1h[32], w2i[32], w2h[32], wi1c[15];
  #pragma unroll
  for (int k=0;k<32;k++){
    w1h[k]=W1hh[g*HID+32*p+k];
    w2i[k]=W2ih[g*HID+32*p+k];
    w2h[k]=W2hh[g*HID+32*p+k];
  }
  const int cbase = p ? 15 : 0;
  const int cn    = p ? 14 : 15;
  #pragma unroll
  for (int j=0;j<15;j++) wi1c[j] = (j<cn) ? W1ih[g*VOC+cbase+j] : 0.f;
  const float biasg = p ? 0.f : (b1ih[g]+b1hh[g]);
  const float bias2 = p ? 0.f : (b2ih[g]+b2hh[g]);

  // state: all 8 lanes of a unit hold identical c (redundant), h in LDS double-buffer
  float c1r[2], c2r[2];
  c1r[0]=c1gp[(b0+0)*HID+m]; c1r[1]=c1gp[(b0+1)*HID+m];
  c2r[0]=0.f; c2r[1]=0.f;
  if (tid<128){
    int u=tid>>6,k=tid&63;
    h1s[0][u][k]=h1gp[(b0+u)*HID+k];
    h2s[0][u][k]=0.f;
  }
  __syncthreads();

  unsigned F = 1u<<SOS;  // verified union mask feeding the frontier step
  int f = 0;             // frontier
  unsigned rr = 0;       // round counter
  int Wcur = 4, streak = 0;
  int pb = 0;            // h double-buffer parity: h1s[pb] = current state

  while (f < TSTEPS){
    const int Wr = (TSTEPS - f < Wcur) ? (TSTEPS - f) : Wcur;
    const unsigned tag = rr + 1u;
    unsigned long long* __restrict__ mrow = mseq + (size_t)(rr&1u)*(WMAX*256);

    if (tid < Wr) u_lds[tid] = 0u;   // safe: last read was before prior round's closing barrier

    // round-constant gate1 input term (frozen mask F)
    float it0 = biasg;
    #pragma unroll
    for (int jj=0;jj<15;jj++) it0 += ((F>>(cbase+jj))&1u) ? wi1c[jj] : 0.f;

    // ---- speculative window ----
    for (int j=0;j<Wr;j++){
      // ph1: gate1 (it0 + W1hh.h1) + LSTM1 activation, fused via shuffles
      float h1n[2];
      #pragma unroll
      for (int u=0;u<2;u++){
        float a0=it0,a1=0.f,a2=0.f,a3=0.f;
        const float4* h4=(const float4*)(&h1s[pb][u][32*p]);
        #pragma unroll
        for (int c=0;c<8;c++){
          float4 qv=h4[c];
          a0=fmaf(qv.x,w1h[4*c+0],a0); a1=fmaf(qv.y,w1h[4*c+1],a1);
          a2=fmaf(qv.z,w1h[4*c+2],a2); a3=fmaf(qv.w,w1h[4*c+3],a3);
        }
        float v=(a0+a1)+(a2+a3);
        v += __shfl_xor(v,1);            // combine halves
        float x2=__shfl_xor(v,2), x4=__shfl_xor(v,4), x6=__shfl_xor(v,6);
        float ig = q==0?v : q==1?x2 : q==2?x4 : x6;
        float fg = q==1?v : q==0?x2 : q==3?x4 : x6;
        float gg = q==2?v : q==3?x2 : q==0?x4 : x6;
        float og = q==3?v : q==2?x2 : q==1?x4 : x6;
        float c = sigmf(fg)*c1r[u] + sigmf(ig)*tanhfast(gg);
        c1r[u]=c; h1n[u]=sigmf(og)*tanhfast(c);
      }
      if ((tid&7)==0){
        h1s[pb^1][0][m]=h1n[0]; h1s[pb^1][1][m]=h1n[1];
        h1ck[j][0][m]=h1n[0];   h1ck[j][1][m]=h1n[1];
        c1ck[j][0][m]=c1r[0];   c1ck[j][1][m]=c1r[1];
      }
      __syncthreads();   // B1: h1 cur visible

      // ph2: gate2 (W2ih.h1cur + W2hh.h2prev) + LSTM2 activation
      float h2n[2];
      #pragma unroll
      for (int u=0;u<2;u++){
        float a0=bias2,a1=0.f,a2=0.f,a3=0.f;
        const float4* i4=(const float4*)(&h1s[pb^1][u][32*p]);
        const float4* h4=(const float4*)(&h2s[pb][u][32*p]);
        #pragma unroll
        for (int c=0;c<8;c++){
          float4 qv=i4[c], wv=h4[c];
          a0=fmaf(qv.x,w2i[4*c+0],a0); a1=fmaf(qv.y,w2i[4*c+1],a1);
          a2=fmaf(qv.z,w2i[4*c+2],a2); a3=fmaf(qv.w,w2i[4*c+3],a3);
          a0=fmaf(wv.x,w2h[4*c+0],a0); a1=fmaf(wv.y,w2h[4*c+1],a1);
          a2=fmaf(wv.z,w2h[4*c+2],a2); a3=fmaf(wv.w,w2h[4*c+3],a3);
        }
        float v=(a0+a1)+(a2+a3);
        v += __shfl_xor(v,1);
        float x2=__shfl_xor(v,2), x4=__shfl_xor(v,4), x6=__shfl_xor(v,6);
        float ig = q==0?v : q==1?x2 : q==2?x4 : x6;
        float fg = q==1?v : q==0?x2 : q==3?x4 : x6;
        float gg = q==2?v : q==3?x2 : q==0?x4 : x6;
        float og = q==3?v : q==2?x2 : q==1?x4 : x6;
        float c = sigmf(fg)*c2r[u] + sigmf(ig)*tanhfast(gg);
        c2r[u]=c; h2n[u]=sigmf(og)*tanhfast(c);
      }
      if ((tid&7)==0){
        h2s[pb^1][0][m]=h2n[0]; h2s[pb^1][1][m]=h2n[1];
        h2ck[j][0][m]=h2n[0];   h2ck[j][1][m]=h2n[1];
        c2ck[j][0][m]=c2r[0];   c2ck[j][1][m]=c2r[1];
      }
      __syncthreads();   // B2: h2 cur visible

      // ph3: classifier + argmax + tagged post (wave 0; other waves run ahead to ph1(j+1))
      if (tid<64){
        const int s = f + j;
        int row=tid>>5, v=tid&31;
        float pv = -INFINITY;
        if (v<VOC){
          float a0=clsb_s[v],a1=0.f,a2=0.f,a3=0.f;
          const float4* h4=(const float4*)h2s[pb^1][row];
          #pragma unroll
          for (int c=0;c<16;c++){
            float4 qv=h4[c];
            a0=fmaf(qv.x,clsW_s[v][4*c+0],a0); a1=fmaf(qv.y,clsW_s[v][4*c+1],a1);
            a2=fmaf(qv.z,clsW_s[v][4*c+2],a2); a3=fmaf(qv.w,clsW_s[v][4*c+3],a3);
          }
          pv=(a0+a1)+(a2+a3);
          out[((size_t)s*BATCH + (size_t)(b0+row))*VOC + v]=pv;
        }
        int ix=v;
        #pragma unroll
        for (int off=16; off>0; off>>=1){
          float ov=__shfl_xor(pv,off);
          int   oi=__shfl_xor(ix,off);
          if (ov>pv || (ov==pv && oi<ix)){ pv=ov; ix=oi; }
        }
        unsigned bit = 1u<<ix;
        unsigned mb  = bit | __shfl_xor(bit,32);
        if (tid==0)
          __hip_atomic_store(&mrow[j*256+blk],
                             ((unsigned long long)tag<<32) | (unsigned long long)mb,
                             __ATOMIC_RELAXED, __HIP_MEMORY_SCOPE_AGENT);
      }
      pb ^= 1;
    }

    // ---- single-phase validation: spin on self-tagged words, union into LDS ----
    for (int w=tid; w<Wr*256; w+=NTHREADS){
      const int jj = w>>8, bb = w&255;
      unsigned long long vv;
      do {
        vv = __hip_atomic_load(&mrow[jj*256+bb], __ATOMIC_RELAXED, __HIP_MEMORY_SCOPE_AGENT);
      } while ((unsigned)(vv>>32) != tag);
      unsigned um = (unsigned)vv & MASK29;
      // jj is wave-uniform (w-ranges of 64 never straddle a 256 boundary): wave-reduce
      um |= __shfl_xor(um,1);  um |= __shfl_xor(um,2);  um |= __shfl_xor(um,4);
      um |= __shfl_xor(um,8);  um |= __shfl_xor(um,16); um |= __shfl_xor(um,32);
      if ((tid&63)==0) atomicOr(&u_lds[jj], um);
    }
    __syncthreads();

    // ---- validate (identical decision in every block) ----
    int jstar = Wr;
    for (int jj=1;jj<Wr;jj++){ if (u_lds[jj-1]!=F){ jstar=jj; break; } }

    if (jstar==Wr){
      F = u_lds[Wr-1]; f += Wr; rr++;
      streak++;
      if (streak>=2 && Wcur<WMAX) Wcur*=2;
    } else {
      // free rollback: restore state after step jstar-1 from checkpoints (no recompute)
      const int jm = jstar-1;
      c1r[0]=c1ck[jm][0][m]; c1r[1]=c1ck[jm][1][m];
      c2r[0]=c2ck[jm][0][m]; c2r[1]=c2ck[jm][1][m];
      if (tid<128){
        int u=tid>>6,k=tid&63;
        h1s[0][u][k]=h1ck[jm][u][k];
        h2s[0][u][k]=h2ck[jm][u][k];
      }
      pb = 0;
      F = u_lds[jm]; f += jstar; rr++;
      streak = 0; Wcur = jstar;
    }
    __syncthreads();   // protects u_lds rezero + restored h before next round
  }
}

extern "C" void kernel_launch(void* const* d_in, const int* in_sizes, int n_in,
                              void* d_out, int out_size, void* d_ws, size_t ws_size,
                              hipStream_t stream)
{
  const float* x     = (const float*)d_in[0];
  const float* eWih0 = (const float*)d_in[1];
  const float* eWhh0 = (const float*)d_in[2];
  const float* ebih0 = (const float*)d_in[3];
  const float* ebhh0 = (const float*)d_in[4];
  const float* eWih1 = (const float*)d_in[5];
  const float* eWhh1 = (const float*)d_in[6];
  const float* ebih1 = (const float*)d_in[7];
  const float* ebhh1 = (const float*)d_in[8];
  const float* d1Wih = (const float*)d_in[9];
  const float* d1Whh = (const float*)d_in[10];
  const float* d1bih = (const float*)d_in[11];
  const float* d1bhh = (const float*)d_in[12];
  const float* d2Wih = (const float*)d_in[13];
  const float* d2Whh = (const float*)d_in[14];
  const float* d2bih = (const float*)d_in[15];
  const float* d2bhh = (const float*)d_in[16];
  const float* clsW  = (const float*)d_in[17];
  const float* clsb  = (const float*)d_in[18];
  float* out = (float*)d_out;

  float* h1g = (float*)d_ws;
  float* c1g = h1g + BATCH*HID;
  unsigned long long* mseq =
      (unsigned long long*)((char*)d_ws + (size_t)(2*BATCH*HID)*sizeof(float));

  hipMemsetAsync(mseq, 0, (size_t)2*WMAX*256*sizeof(unsigned long long), stream);

  enc_kernel<<<ENC_BLOCKS, NTHREADS, 0, stream>>>(
      x, eWih0,eWhh0,ebih0,ebhh0, eWih1,eWhh1,ebih1,ebhh1, h1g,c1g);

  void* args[] = { (void*)&h1g, (void*)&c1g,
                   (void*)&d1Wih,(void*)&d1Whh,(void*)&d1bih,(void*)&d1bhh,
                   (void*)&d2Wih,(void*)&d2Whh,(void*)&d2bih,(void*)&d2bhh,
                   (void*)&clsW,(void*)&clsb,(void*)&out,
                   (void*)&mseq };
  hipLaunchCooperativeKernel((void*)dec_kernel, dim3(DEC_BLOCKS), dim3(NTHREADS),
                             args, 0, stream);
}